// Round 12
// baseline (107.254 us; speedup 1.0000x reference)
//
#include <hip/hip_runtime.h>
#include <hip/hip_bf16.h>

#define H 500
#define D_IN 512
#define D_OUT 100
#define STEPS 49
#define NWG 4
#define NPROD 63
#define NBLK (NWG + NPROD + STEPS)   // 4 + 63 + 49 = 116
#define SENT 0xFFFFFFFFu

typedef _Float16 h2_t __attribute__((ext_vector_type(2)));

#if defined(__has_builtin)
#if __has_builtin(__builtin_amdgcn_fdot2)
#define HAVE_FDOT2 1
#endif
#endif

__device__ __forceinline__ float fdot2f(h2_t a, h2_t b, float c) {
#ifdef HAVE_FDOT2
    return __builtin_amdgcn_fdot2(a, b, c, false);
#else
    return c + (float)a[0] * (float)b[0] + (float)a[1] * (float)b[1];
#endif
}
__device__ __forceinline__ h2_t bch2(unsigned u) { return __builtin_bit_cast(h2_t, u); }
__device__ __forceinline__ unsigned pk(float a, float b) {
    return __builtin_bit_cast(unsigned, h2_t{(_Float16)a, (_Float16)b});
}
__device__ __forceinline__ float tanh_fast(float x) {
    const float e = __expf(2.f * x);
    return 1.f - 2.f / (e + 1.f);
}
__device__ __forceinline__ int clen(int g) { return (g < 3) ? 128 : (H - 384); }  // 116
__device__ __forceinline__ unsigned aload(const float* p) {
    return __builtin_bit_cast(unsigned,
        __hip_atomic_load(p, __ATOMIC_RELAXED, __HIP_MEMORY_SCOPE_AGENT));
}
__device__ __forceinline__ void astore(float* p, float v) {
    __hip_atomic_store(p, v, __ATOMIC_RELAXED, __HIP_MEMORY_SCOPE_AGENT);
}

// ---------------- one fused kernel, role by blockIdx ----------------
// blocks 0..3            workers   : r11 column-split scan (proven 1.57us/step)
// blocks 4..66           producers : xproj rows [8p, 8p+8) -> sentinel buffer
// blocks 67..115         consumers : block t polls Hs[t] rows, computes out[t]
// Edges: producers -> workers (xproj), workers -> workers (part),
// workers -> consumers (Hs). All one-shot sentinel dataflow, agent scope.
// 116 blocks, 131.6KB LDS each -> 1 block/CU, all co-resident, acyclic waits.
__global__ void __launch_bounds__(512, 1)
k_fused(const float* __restrict__ hidden0, const float* __restrict__ W_hh,
        const float* __restrict__ x, const float* __restrict__ W_ih,
        const float* __restrict__ b_ih, const float* __restrict__ b_hh,
        const float* __restrict__ W_out, const float* __restrict__ b_out,
        float* part, float* xproj, float* Hs, float* __restrict__ out) {
    __shared__ uint4 wl[16 * 512];                  // 131072 B (workers; consumers reuse)
    __shared__ __align__(16) _Float16 hch[2][128];  // 512 B

    const int tid = threadIdx.x;
    const int bid = blockIdx.x;

    if (bid >= NWG && bid < NWG + NPROD) {
        // ---------------- producer: xproj rows [8p, 8p+8), one per wave ----------------
        const int p = bid - NWG;
        const int wv = tid >> 6, lane = tid & 63;
        const int r = p * 8 + wv;
        if (r >= H) return;
        float wr8[8];
#pragma unroll
        for (int k = 0; k < 8; k++) wr8[k] = W_ih[r * D_IN + k * 64 + lane];
        float pv[STEPS];
#pragma unroll
        for (int t = 0; t < STEPS; t++) pv[t] = 0.f;
#pragma unroll
        for (int k = 0; k < 8; k++) {
            const float* xr = x + (size_t)(k * 64 + lane) * STEPS;
#pragma unroll
            for (int t = 0; t < STEPS; t++) pv[t] = fmaf(wr8[k], xr[t], pv[t]);
        }
#pragma unroll
        for (int t = 0; t < STEPS; t++) {
            float v = pv[t];
            v += __shfl_xor(v, 32); v += __shfl_xor(v, 16); v += __shfl_xor(v, 8);
            v += __shfl_xor(v, 4);  v += __shfl_xor(v, 2);  v += __shfl_xor(v, 1);
            pv[t] = v;
        }
        if (lane == 0) {
            const float b = b_ih[r] + b_hh[r];
            for (int t = 0; t < STEPS; t++) astore(&xproj[t * 512 + r], pv[t] + b);
        }
        return;
    }

    if (bid >= NWG) {
        // ---------------- consumer: out[t][:] once Hs row t lands ----------------
        const int t = bid - NWG - NPROD;            // 0..48
        float* hsm = (float*)wl;                    // reuse LDS
        if (tid < H) {
            unsigned hb;
            do { hb = aload(&Hs[t * 512 + tid]); } while (hb == SENT);
            hsm[tid] = __builtin_bit_cast(float, hb);
        }
        __syncthreads();
        if (tid < D_OUT) {
            const float4* wr = (const float4*)(W_out + tid * H);   // 2000B rows, 16B-aligned
            const float4* hr = (const float4*)hsm;                 // broadcast reads
            float acc = b_out[tid];
#pragma unroll 5
            for (int i = 0; i < 125; i++) {
                const float4 wv = wr[i];
                const float4 hv = hr[i];
                acc = fmaf(wv.x, hv.x, acc);
                acc = fmaf(wv.y, hv.y, acc);
                acc = fmaf(wv.z, hv.z, acc);
                acc = fmaf(wv.w, hv.w, acc);
            }
            out[t * D_OUT + tid] = tanh_fast(acc);
        }
        return;
    }

    // ---------------- worker g = bid: column-split scan (r11 structure) ----------------
    const int g = bid;
    const int rr = tid >> 2, sub = tid & 3;
    const int myLen = clen(g);

    // preamble: W_hh[:, 128g + 32sub .. +32), rows 128d+rr -> LDS f16
#pragma unroll
    for (int d = 0; d < 4; d++) {
        uint4 u[4] = {{0,0,0,0},{0,0,0,0},{0,0,0,0},{0,0,0,0}};
        if (rr < clen(d)) {
            const int row = 128 * d + rr;
            const float* rowp = W_hh + (size_t)row * H + 128 * g + 32 * sub;
            const int cmax = myLen - 32 * sub;
            if (cmax >= 32) {
#pragma unroll
                for (int q8 = 0; q8 < 4; q8++) {
                    const float4 f0 = *(const float4*)(rowp + 8 * q8);
                    const float4 f1 = *(const float4*)(rowp + 8 * q8 + 4);
                    u[q8].x = pk(f0.x, f0.y); u[q8].y = pk(f0.z, f0.w);
                    u[q8].z = pk(f1.x, f1.y); u[q8].w = pk(f1.z, f1.w);
                }
            } else {
                float f[32];
#pragma unroll
                for (int cc = 0; cc < 32; cc++) f[cc] = (cc < cmax) ? rowp[cc] : 0.f;
#pragma unroll
                for (int q8 = 0; q8 < 4; q8++) {
                    u[q8].x = pk(f[8*q8+0], f[8*q8+1]);
                    u[q8].y = pk(f[8*q8+2], f[8*q8+3]);
                    u[q8].z = pk(f[8*q8+4], f[8*q8+5]);
                    u[q8].w = pk(f[8*q8+6], f[8*q8+7]);
                }
            }
        }
#pragma unroll
        for (int c = 0; c < 4; c++) wl[(d * 4 + c) * 512 + tid] = u[c];
    }
    if (tid < 128) hch[0][tid] = (tid < myLen) ? (_Float16)hidden0[128 * g + tid]
                                               : (_Float16)0.f;
    else if (tid < 256) hch[1][tid - 128] = (_Float16)0.f;
    __syncthreads();

#pragma unroll 1
    for (int t = 0; t < STEPS; ++t) {
        const int cur = t & 1;
        // speculative xproj load (sentinel-checked only at consume)
        unsigned xb = SENT;
        const float* xpp = &xproj[t * 512 + 128 * g + rr];
        if (sub == 0 && rr < myLen) xb = aload(xpp);

        const uint4* hc = (const uint4*)&hch[cur][0];
        uint4 hv4[4];
#pragma unroll
        for (int c = 0; c < 4; c++) hv4[c] = hc[sub * 4 + c];

        float own = 0.f;
#pragma unroll
        for (int k = 0; k < 4; k++) {
            const int d = (g + 1 + k) & 3;          // k=0..2 remote, k=3 own
            float s = 0.f;
#pragma unroll
            for (int c = 0; c < 4; c++) {
                const uint4 w = wl[(d * 4 + c) * 512 + tid];
                const uint4 hb = hv4[c];
                s = fdot2f(bch2(w.x), bch2(hb.x), s);
                s = fdot2f(bch2(w.y), bch2(hb.y), s);
                s = fdot2f(bch2(w.z), bch2(hb.z), s);
                s = fdot2f(bch2(w.w), bch2(hb.w), s);
            }
            s += __shfl_xor(s, 1);
            s += __shfl_xor(s, 2);
            if (k < 3) {
                if (sub == 0)
                    astore(&part[((t * 4 + d) * 4 + g) * 128 + rr], s);
            } else own = s;
        }

        if (sub == 0 && rr < myLen) {
            const int g1 = (g + 1) & 3, g2 = (g + 2) & 3, g3 = (g + 3) & 3;
            const float* pb = &part[(t * 4 + g) * 4 * 128];
            unsigned b1 = SENT, b2 = SENT, b3 = SENT;
            do {
                if (b1 == SENT) b1 = aload(&pb[g1 * 128 + rr]);
                if (b2 == SENT) b2 = aload(&pb[g2 * 128 + rr]);
                if (b3 == SENT) b3 = aload(&pb[g3 * 128 + rr]);
            } while (b1 == SENT || b2 == SENT || b3 == SENT);
            while (xb == SENT) xb = aload(xpp);     // usually already resolved
            const float tot = own + __builtin_bit_cast(float, b1)
                                  + __builtin_bit_cast(float, b2)
                                  + __builtin_bit_cast(float, b3)
                                  + __builtin_bit_cast(float, xb);
            const float hv = tanh_fast(tot);
            astore(&Hs[t * 512 + 128 * g + rr], hv);  // consumers poll this
            hch[cur ^ 1][rr] = (_Float16)hv;
        }
        __syncthreads();
    }
}

extern "C" void kernel_launch(void* const* d_in, const int* in_sizes, int n_in,
                              void* d_out, int out_size, void* d_ws, size_t ws_size,
                              hipStream_t stream) {
    const float* x       = (const float*)d_in[0];
    const float* hidden0 = (const float*)d_in[1];
    const float* W_ih    = (const float*)d_in[2];
    const float* W_hh    = (const float*)d_in[3];
    const float* b_ih    = (const float*)d_in[4];
    const float* b_hh    = (const float*)d_in[5];
    const float* W_out   = (const float*)d_in[6];
    const float* b_out   = (const float*)d_in[7];
    float* out = (float*)d_out;

    char* ws = (char*)d_ws;
    float* part  = (float*)ws;                     // 49*4*4*128*4 = 401408
    float* xproj = (float*)(ws + 401408);          // 49*512*4    = 100352
    float* Hs    = (float*)(ws + 501760);          // 100352  (sentinel total 602112)

    hipMemsetAsync(ws, 0xFF, 602112, stream);      // one sentinel memset for all edges
    k_fused<<<NBLK, 512, 0, stream>>>(hidden0, W_hh, x, W_ih, b_ih, b_hh,
                                      W_out, b_out, part, xproj, Hs, out);
}